// Round 9
// baseline (268.610 us; speedup 1.0000x reference)
//
#include <hip/hip_runtime.h>

#define NNODES 50000
#define NEDGES 640000
#define D 128

typedef unsigned short u16;
typedef unsigned int u32;
typedef __bf16 bf16x8 __attribute__((ext_vector_type(8)));
typedef float f32x4 __attribute__((ext_vector_type(4)));
typedef float f32x2 __attribute__((ext_vector_type(2)));
union AB { uint4 u4; bf16x8 f; };

__device__ __forceinline__ u16 f2b(float f) {
    u32 u = __float_as_uint(f);
    return (u16)((u + 0x7fffu + ((u >> 16) & 1u)) >> 16);
}
__device__ __forceinline__ u32 pack2(float lo, float hi) {
    return (u32)f2b(lo) | ((u32)f2b(hi) << 16);
}
__device__ __forceinline__ float blo(u32 v) { return __uint_as_float(v << 16); }
__device__ __forceinline__ float bhi(u32 v) { return __uint_as_float(v & 0xffff0000u); }

// packed accumulate: 4x f32x2 += unpacked bf16 pairs (targets v_pk_add_f32)
__device__ __forceinline__ void acc8p(f32x2* a, uint4 v) {
    a[0] += (f32x2){blo(v.x), bhi(v.x)};
    a[1] += (f32x2){blo(v.y), bhi(v.y)};
    a[2] += (f32x2){blo(v.z), bhi(v.z)};
    a[3] += (f32x2){blo(v.w), bhi(v.w)};
}

// ---------------- weight prep + x conversion (float4) + edge histogram ----------------
__global__ void k_prep(const float* __restrict__ W1, const float* __restrict__ W2,
                       const float* __restrict__ fw, const float* __restrict__ x,
                       const int* __restrict__ dst,
                       u16* __restrict__ wT1, u16* __restrict__ wT2,
                       u16* __restrict__ fwTc, uint2* __restrict__ xb,
                       int* __restrict__ cnt, int* __restrict__ epos) {
    int idx = blockIdx.x * 256 + threadIdx.x;
    if (idx < 3 * 16384) {
        int l = idx >> 14, r = idx & 16383, n = r >> 7, k = r & 127;
        wT1[idx] = f2b(W1[l * 16384 + k * 128 + n]);
        wT2[idx] = f2b(W2[l * 16384 + k * 128 + n]);
    }
    if (idx < 4 * 16384) {
        int ch = idx >> 14, r = idx & 16383, n = r >> 7, k = r & 127;
        fwTc[idx] = f2b(fw[(ch * 128 + k) * 128 + n]);
    }
    if (idx < NEDGES) {
        epos[idx] = atomicAdd(&cnt[dst[idx]], 1);
    }
    if (idx < NNODES * 32) {  // float4 per thread: 16B load, 8B store
        float4 v = ((const float4*)x)[idx];
        xb[idx] = make_uint2(pack2(v.x, v.y), pack2(v.z, v.w));
    }
}

// ---------------- scan: per-block scan + last-block scans the block sums ----------------
// rp stays RAW (per-block exclusive prefix); consumers add bsum[i>>8] on the fly.
__global__ void k_scan1(const int* __restrict__ cnt, int* __restrict__ rp,
                        int* __restrict__ bsum, int* __restrict__ counter) {
    __shared__ int s[256];
    __shared__ int lastBlk;
    int tid = threadIdx.x;
    int i = blockIdx.x * 256 + tid;
    int v = (i < NNODES) ? cnt[i] : 0;
    s[tid] = v;
    __syncthreads();
    for (int off = 1; off < 256; off <<= 1) {
        int t = (tid >= off) ? s[tid - off] : 0;
        __syncthreads();
        s[tid] += t;
        __syncthreads();
    }
    if (i < NNODES) rp[i] = s[tid] - v;
    if (tid == 255)
        __hip_atomic_store(&bsum[blockIdx.x], s[255], __ATOMIC_RELEASE,
                           __HIP_MEMORY_SCOPE_AGENT);
    __syncthreads();  // bsum store issued; s free for reuse
    if (tid == 0) {
        int n = __hip_atomic_fetch_add(counter, 1, __ATOMIC_ACQ_REL,
                                       __HIP_MEMORY_SCOPE_AGENT);
        lastBlk = (n == (int)gridDim.x - 1);
    }
    __syncthreads();
    if (lastBlk) {  // whole last block: exclusive-scan bsum[0..nb)
        int nb = gridDim.x;
        int v2 = (tid < nb)
                     ? __hip_atomic_load(&bsum[tid], __ATOMIC_ACQUIRE,
                                         __HIP_MEMORY_SCOPE_AGENT)
                     : 0;
        s[tid] = v2;
        __syncthreads();
        for (int off = 1; off < 256; off <<= 1) {
            int t = (tid >= off) ? s[tid - off] : 0;
            __syncthreads();
            s[tid] += t;
            __syncthreads();
        }
        if (tid < nb) bsum[tid] = s[tid] - v2;
    }
}

// ---------------- scatter: pure store, no atomic; final rp = rp[d]+bsum[d>>8] ----
__global__ void k_scatter(const int* __restrict__ src, const int* __restrict__ dst,
                          const int* __restrict__ rp, const int* __restrict__ bsum,
                          const int* __restrict__ epos, int* __restrict__ srcs) {
    int e = blockIdx.x * 256 + threadIdx.x;
    if (e < NEDGES) {
        int d = dst[e];
        srcs[rp[d] + bsum[d >> 8] + epos[e]] = src[e];
    }
}

// ---------------- aggregation: 16-deep gather batch, packed f32x2 accumulate --------
// 16 lanes/node, one node per group, grid = 50000*16/256 = 3125 (exact).
// No launch bound (r7: forcing 8/SIMD spilled everything). All 16 batch loads
// issued up-front; accumulate predicated; acc held as 4x f32x2 -> v_pk_add_f32.
__global__ void k_agg(const uint4* __restrict__ h4, const int* __restrict__ rp,
                      const int* __restrict__ bsum, const int* __restrict__ srcs,
                      const float* __restrict__ epsp, uint4* __restrict__ z4) {
    int tid = threadIdx.x;
    int c = tid & 15;                          // 16B chunk of the 256B row
    int node = (blockIdx.x * 256 + tid) >> 4;  // exact coverage
    int gbase = tid & 48;                      // group base lane within wave
    float sc = 1.0f + epsp[0];

    uint4 sv = h4[node * 16 + c];
    f32x2 acc[4];
    acc[0] = (f32x2){sc * blo(sv.x), sc * bhi(sv.x)};
    acc[1] = (f32x2){sc * blo(sv.y), sc * bhi(sv.y)};
    acc[2] = (f32x2){sc * blo(sv.z), sc * bhi(sv.z)};
    acc[3] = (f32x2){sc * blo(sv.w), sc * bhi(sv.w)};

    int beg = rp[node] + bsum[node >> 8];
    int end = (node + 1 == NNODES) ? NEDGES : rp[node + 1] + bsum[(node + 1) >> 8];
    for (int base = beg; base < end; base += 16) {
        int n = end - base; if (n > 16) n = 16;
        int myidx = (base + c < end) ? srcs[base + c] : 0;
        uint4 v[16];
#pragma unroll
        for (int j = 0; j < 16; ++j) {
            int s = __shfl(myidx, gbase + j, 64);  // j>=n lanes shuffled idx 0
            v[j] = h4[s * 16 + c];                 // row 0 re-reads are L1-hot
        }
#pragma unroll
        for (int j = 0; j < 16; ++j)
            if (j < n) acc8p(acc, v[j]);
    }

    uint4 o;
    o.x = pack2(acc[0].x, acc[0].y); o.y = pack2(acc[1].x, acc[1].y);
    o.z = pack2(acc[2].x, acc[2].y); o.w = pack2(acc[3].x, acc[3].y);
    z4[node * 16 + c] = o;
}

// ---------------- layer MLP: 64-row tiles, 3 blocks/CU, grid 782 --------------------
// r8 diagnosis: 128-row tiles -> 391 blocks at 2/CU = 1.53 resident blocks/CU;
// half the CUs hold ONE block so the 6-barrier serial chain has nothing to
// overlap with. 64-row: Tb=16KB -> LDS 48KB -> 3 blocks/CU, grid 782 (~3.05/CU):
// every CU overlaps one block's staging with two others' MFMA.
__launch_bounds__(256, 3)
__global__ void k_mlp64(const u16* __restrict__ A, const u16* __restrict__ wT1g,
                        const float* __restrict__ b1, const u16* __restrict__ wT2g,
                        const float* __restrict__ b2, u16* __restrict__ H) {
    __shared__ u16 Tb[64 * 128];     // 16 KB
    __shared__ u16 wbuf[128 * 128];  // 32 KB
    uint4* Tb4 = (uint4*)Tb;
    uint4* wb4 = (uint4*)wbuf;
    int tid = threadIdx.x;
    int r0 = blockIdx.x * 64;
    int wave = tid >> 6, lane = tid & 63, l16 = lane & 15, quad = lane >> 4;

    // stage W1^T (swizzled)
    {
        const uint4* g = (const uint4*)wT1g;
        for (int i = tid; i < 2048; i += 256) {
            int n = i >> 4, ch = i & 15;
            wb4[n * 16 + ((ch + n) & 15)] = g[i];
        }
    }

    // A-fragments straight from global: wave owns 16 rows
    AB a[4];
    {
        int row = r0 + wave * 16 + l16;
#pragma unroll
        for (int kb = 0; kb < 4; ++kb) {
            if (row < NNODES)
                a[kb].u4 = *(const uint4*)&A[row * 128 + kb * 32 + quad * 8];
            else
                a[kb].u4 = make_uint4(0, 0, 0, 0);
        }
    }
    __syncthreads();  // wbuf(W1) ready

    f32x4 acc[8];
#pragma unroll
    for (int col = 0; col < 8; ++col) {
        float bv = b1[col * 16 + l16];
        acc[col] = (f32x4){bv, bv, bv, bv};
    }
#pragma unroll
    for (int col = 0; col < 8; ++col) {
#pragma unroll
        for (int kb = 0; kb < 4; ++kb) {
            AB b;
            int n = col * 16 + l16;
            b.u4 = wb4[n * 16 + ((kb * 4 + quad + n) & 15)];
            acc[col] = __builtin_amdgcn_mfma_f32_16x16x32_bf16(a[kb].f, b.f, acc[col], 0, 0, 0);
        }
    }

    // T = relu -> Tb (swizzled scalar u16 stores; each wave writes only its 16 rows)
#pragma unroll
    for (int col = 0; col < 8; ++col)
#pragma unroll
        for (int r = 0; r < 4; ++r) {
            int row = wave * 16 + quad * 4 + r;
            int kcol = col * 16 + l16;
            int ch = kcol >> 3;
            Tb[row * 128 + ((ch + row) & 15) * 8 + (kcol & 7)] =
                f2b(fmaxf(acc[col][r], 0.f));
        }
    __syncthreads();  // all GEMM1 wbuf reads done -> wbuf overwritable

    // stage W2^T (swizzled, overwrite wbuf)
    {
        const uint4* g = (const uint4*)wT2g;
        for (int i = tid; i < 2048; i += 256) {
            int n = i >> 4, ch = i & 15;
            wb4[n * 16 + ((ch + n) & 15)] = g[i];
        }
    }
    AB a2[4];
    {
        int m = wave * 16 + l16;  // wave reads only its own Tb rows
#pragma unroll
        for (int kb = 0; kb < 4; ++kb)
            a2[kb].u4 = Tb4[m * 16 + ((kb * 4 + quad + m) & 15)];
    }
    __syncthreads();  // wbuf (W2) ready

#pragma unroll
    for (int col = 0; col < 8; ++col) {
        float bv = b2[col * 16 + l16];
        acc[col] = (f32x4){bv, bv, bv, bv};
    }
#pragma unroll
    for (int col = 0; col < 8; ++col) {
#pragma unroll
        for (int kb = 0; kb < 4; ++kb) {
            AB b;
            int n = col * 16 + l16;
            b.u4 = wb4[n * 16 + ((kb * 4 + quad + n) & 15)];
            acc[col] = __builtin_amdgcn_mfma_f32_16x16x32_bf16(a2[kb].f, b.f, acc[col], 0, 0, 0);
        }
    }

    // h = relu -> Tb (each wave overwrites only its own rows; a2 already in regs)
#pragma unroll
    for (int col = 0; col < 8; ++col)
#pragma unroll
        for (int r = 0; r < 4; ++r) {
            int row = wave * 16 + quad * 4 + r;
            int kcol = col * 16 + l16;
            int ch = kcol >> 3;
            Tb[row * 128 + ((ch + row) & 15) * 8 + (kcol & 7)] =
                f2b(fmaxf(acc[col][r], 0.f));
        }
    __syncthreads();  // Tb (h) ready for cross-wave copy

    // coalesced copy Tb -> H (de-swizzle)
    for (int i = tid; i < 1024; i += 256) {
        int r = i >> 4, ch = i & 15;
        int grow = r0 + r;
        if (grow < NNODES)
            *(uint4*)&H[grow * 128 + ch * 8] = Tb4[r * 16 + ((ch + r) & 15)];
    }
}

// ---------------- final MLP (layer 3 + fused output projection), 128-row tiles ------
__launch_bounds__(256, 2)
__global__ void k_mlpF(const u16* __restrict__ A, const u16* __restrict__ wT1g,
                       const float* __restrict__ b1, const u16* __restrict__ wT2g,
                       const float* __restrict__ b2,
                       const u16* __restrict__ xbg, const u16* __restrict__ h1g,
                       const u16* __restrict__ h2g, const u16* __restrict__ fwTc,
                       const float* __restrict__ fb, float* __restrict__ out) {
    __shared__ u16 Tb[128 * 128];    // 32 KB
    __shared__ u16 wbuf[128 * 128];  // 32 KB
    uint4* Tb4 = (uint4*)Tb;
    uint4* wb4 = (uint4*)wbuf;
    int tid = threadIdx.x;
    int r0 = blockIdx.x * 128;
    int wave = tid >> 6, lane = tid & 63, l16 = lane & 15, quad = lane >> 4;

    // stage W1^T (swizzled)
    {
        const uint4* g = (const uint4*)wT1g;
        for (int i = tid; i < 2048; i += 256) {
            int n = i >> 4, ch = i & 15;
            wb4[n * 16 + ((ch + n) & 15)] = g[i];
        }
    }

    AB a[2][4];
#pragma unroll
    for (int s = 0; s < 2; ++s) {
        int row = r0 + wave * 32 + s * 16 + l16;
#pragma unroll
        for (int kb = 0; kb < 4; ++kb) {
            if (row < NNODES)
                a[s][kb].u4 = *(const uint4*)&A[row * 128 + kb * 32 + quad * 8];
            else
                a[s][kb].u4 = make_uint4(0, 0, 0, 0);
        }
    }
    __syncthreads();

    f32x4 acc[2][8];
#pragma unroll
    for (int col = 0; col < 8; ++col) {
        float bv = b1[col * 16 + l16];
        acc[0][col] = (f32x4){bv, bv, bv, bv};
        acc[1][col] = (f32x4){bv, bv, bv, bv};
    }
#pragma unroll
    for (int col = 0; col < 8; ++col) {
#pragma unroll
        for (int kb = 0; kb < 4; ++kb) {
            AB b;
            int n = col * 16 + l16;
            b.u4 = wb4[n * 16 + ((kb * 4 + quad + n) & 15)];
            acc[0][col] = __builtin_amdgcn_mfma_f32_16x16x32_bf16(a[0][kb].f, b.f, acc[0][col], 0, 0, 0);
            acc[1][col] = __builtin_amdgcn_mfma_f32_16x16x32_bf16(a[1][kb].f, b.f, acc[1][col], 0, 0, 0);
        }
    }

    // T = relu -> Tb
#pragma unroll
    for (int s = 0; s < 2; ++s)
#pragma unroll
        for (int col = 0; col < 8; ++col)
#pragma unroll
            for (int r = 0; r < 4; ++r) {
                int row = wave * 32 + s * 16 + quad * 4 + r;
                int kcol = col * 16 + l16;
                int ch = kcol >> 3;
                Tb[row * 128 + ((ch + row) & 15) * 8 + (kcol & 7)] =
                    f2b(fmaxf(acc[s][col][r], 0.f));
            }
    __syncthreads();

    // stage W2^T (swizzled, overwrite wbuf)
    {
        const uint4* g = (const uint4*)wT2g;
        for (int i = tid; i < 2048; i += 256) {
            int n = i >> 4, ch = i & 15;
            wb4[n * 16 + ((ch + n) & 15)] = g[i];
        }
    }
    AB a2[2][4];
#pragma unroll
    for (int s = 0; s < 2; ++s) {
        int m = wave * 32 + s * 16 + l16;
#pragma unroll
        for (int kb = 0; kb < 4; ++kb)
            a2[s][kb].u4 = Tb4[m * 16 + ((kb * 4 + quad + m) & 15)];
    }
    __syncthreads();  // wbuf (W2) ready; Tb reads drained

#pragma unroll
    for (int col = 0; col < 8; ++col) {
        float bv = b2[col * 16 + l16];
        acc[0][col] = (f32x4){bv, bv, bv, bv};
        acc[1][col] = (f32x4){bv, bv, bv, bv};
    }
#pragma unroll
    for (int col = 0; col < 8; ++col) {
#pragma unroll
        for (int kb = 0; kb < 4; ++kb) {
            AB b;
            int n = col * 16 + l16;
            b.u4 = wb4[n * 16 + ((kb * 4 + quad + n) & 15)];
            acc[0][col] = __builtin_amdgcn_mfma_f32_16x16x32_bf16(a2[0][kb].f, b.f, acc[0][col], 0, 0, 0);
            acc[1][col] = __builtin_amdgcn_mfma_f32_16x16x32_bf16(a2[1][kb].f, b.f, acc[1][col], 0, 0, 0);
        }
    }

    // h = relu -> Tb
#pragma unroll
    for (int s = 0; s < 2; ++s)
#pragma unroll
        for (int col = 0; col < 8; ++col)
#pragma unroll
            for (int r = 0; r < 4; ++r) {
                int row = wave * 32 + s * 16 + quad * 4 + r;
                int kcol = col * 16 + l16;
                int ch = kcol >> 3;
                Tb[row * 128 + ((ch + row) & 15) * 8 + (kcol & 7)] =
                    f2b(fmaxf(acc[s][col][r], 0.f));
            }

    // ---- fused final projection: out = concat(x,h1,h2,h3) @ fw + fb ----
#pragma unroll
    for (int col = 0; col < 8; ++col) {
        float bv = fb[col * 16 + l16];
        acc[0][col] = (f32x4){bv, bv, bv, bv};
        acc[1][col] = (f32x4){bv, bv, bv, bv};
    }
    const u16* chin[3] = {xbg, h1g, h2g};
    AB afN[2][4];
#pragma unroll
    for (int s = 0; s < 2; ++s) {  // prefetch chunk 0 (xb)
        int row = r0 + wave * 32 + s * 16 + l16;
#pragma unroll
        for (int kb = 0; kb < 4; ++kb)
            afN[s][kb].u4 = (row < NNODES)
                                ? *(const uint4*)&xbg[row * 128 + kb * 32 + quad * 8]
                                : make_uint4(0, 0, 0, 0);
    }
#pragma unroll
    for (int chn = 0; chn < 4; ++chn) {
        __syncthreads();  // prev wbuf MFMA reads drained; (chn0) Tb h3 stores visible
        {
            const uint4* g = (const uint4*)(fwTc + chn * 16384);
            for (int i = tid; i < 2048; i += 256) {
                int n = i >> 4, ch = i & 15;
                wb4[n * 16 + ((ch + n) & 15)] = g[i];
            }
        }
        AB af[2][4];
#pragma unroll
        for (int s = 0; s < 2; ++s)
#pragma unroll
            for (int kb = 0; kb < 4; ++kb) af[s][kb] = afN[s][kb];
        if (chn < 2) {  // prefetch next global chunk (h1 or h2)
            const u16* cp = chin[chn + 1];
#pragma unroll
            for (int s = 0; s < 2; ++s) {
                int row = r0 + wave * 32 + s * 16 + l16;
#pragma unroll
                for (int kb = 0; kb < 4; ++kb)
                    afN[s][kb].u4 = (row < NNODES)
                                        ? *(const uint4*)&cp[row * 128 + kb * 32 + quad * 8]
                                        : make_uint4(0, 0, 0, 0);
            }
        } else if (chn == 2) {  // prefetch h3 from Tb (stable throughout)
#pragma unroll
            for (int s = 0; s < 2; ++s) {
                int m = wave * 32 + s * 16 + l16;
#pragma unroll
                for (int kb = 0; kb < 4; ++kb)
                    afN[s][kb].u4 = Tb4[m * 16 + ((kb * 4 + quad + m) & 15)];
            }
        }
        __syncthreads();  // wbuf (fw chunk) ready
#pragma unroll
        for (int col = 0; col < 8; ++col) {
#pragma unroll
            for (int kb = 0; kb < 4; ++kb) {
                AB b;
                int n = col * 16 + l16;
                b.u4 = wb4[n * 16 + ((kb * 4 + quad + n) & 15)];
                acc[0][col] = __builtin_amdgcn_mfma_f32_16x16x32_bf16(af[0][kb].f, b.f, acc[0][col], 0, 0, 0);
                acc[1][col] = __builtin_amdgcn_mfma_f32_16x16x32_bf16(af[1][kb].f, b.f, acc[1][col], 0, 0, 0);
            }
        }
    }
#pragma unroll
    for (int s = 0; s < 2; ++s)
#pragma unroll
        for (int col = 0; col < 8; ++col)
#pragma unroll
            for (int r = 0; r < 4; ++r) {
                int row = r0 + wave * 32 + s * 16 + quad * 4 + r;
                if (row < NNODES)
                    __builtin_nontemporal_store(acc[s][col][r],
                                                &out[row * 128 + col * 16 + l16]);
            }
}

extern "C" void kernel_launch(void* const* d_in, const int* in_sizes, int n_in,
                              void* d_out, int out_size, void* d_ws, size_t ws_size,
                              hipStream_t stream) {
    const float* x   = (const float*)d_in[0];
    const int*   ei  = (const int*)d_in[1];
    const float* W1  = (const float*)d_in[2];
    const float* b1  = (const float*)d_in[3];
    const float* W2  = (const float*)d_in[4];
    const float* b2  = (const float*)d_in[5];
    const float* eps = (const float*)d_in[6];
    const float* fw  = (const float*)d_in[7];
    const float* fb  = (const float*)d_in[8];
    float* out = (float*)d_out;

    const int* srcA = ei;
    const int* dstA = ei + NEDGES;

    char* p = (char*)d_ws;
    size_t off = 0;
    auto take = [&](size_t bytes) {
        char* r = p + off;
        off = (off + bytes + 255) & ~(size_t)255;
        return r;
    };
    int* rp   = (int*)take((NNODES + 1) * sizeof(int));
    int* cnt  = (int*)take((NNODES + 1) * sizeof(int));  // [NNODES] = scan arrival counter
    int* bsum = (int*)take(256 * sizeof(int));
    int* epos = (int*)take(NEDGES * sizeof(int));
    int* srcs = (int*)take(NEDGES * sizeof(int));
    u16* wT1  = (u16*)take(3 * 16384 * sizeof(u16));
    u16* wT2  = (u16*)take(3 * 16384 * sizeof(u16));
    u16* fwTc = (u16*)take(4 * 16384 * sizeof(u16));
    u16* xb   = (u16*)take((size_t)NNODES * D * sizeof(u16));
    u16* zb   = (u16*)take((size_t)NNODES * D * sizeof(u16));
    u16* hb1  = (u16*)take((size_t)NNODES * D * sizeof(u16));
    u16* hb2  = (u16*)take((size_t)NNODES * D * sizeof(u16));
    (void)ws_size; (void)in_sizes; (void)n_in; (void)out_size;

    (void)hipMemsetAsync(cnt, 0, (NNODES + 1) * sizeof(int), stream);

    int nb = (NNODES + 255) / 256;  // 196
    k_prep<<<(NNODES * 32 + 255) / 256, 256, 0, stream>>>(W1, W2, fw, x, dstA,
                                                          wT1, wT2, fwTc, (uint2*)xb,
                                                          cnt, epos);
    k_scan1<<<nb, 256, 0, stream>>>(cnt, rp, bsum, cnt + NNODES);
    k_scatter<<<(NEDGES + 255) / 256, 256, 0, stream>>>(srcA, dstA, rp, bsum, epos, srcs);

    int gm64 = (NNODES + 63) / 64;  // 782
    // layer 1
    k_agg<<<NNODES * 16 / 256, 256, 0, stream>>>((const uint4*)xb, rp, bsum, srcs, eps + 0, (uint4*)zb);
    k_mlp64<<<gm64, 256, 0, stream>>>(zb, wT1, b1, wT2, b2, hb1);
    // layer 2
    k_agg<<<NNODES * 16 / 256, 256, 0, stream>>>((const uint4*)hb1, rp, bsum, srcs, eps + 1, (uint4*)zb);
    k_mlp64<<<gm64, 256, 0, stream>>>(zb, wT1 + 16384, b1 + D, wT2 + 16384, b2 + D, hb2);
    // layer 3 + fused final projection (128-row tiles, grid 391)
    k_agg<<<NNODES * 16 / 256, 256, 0, stream>>>((const uint4*)hb2, rp, bsum, srcs, eps + 2, (uint4*)zb);
    k_mlpF<<<(NNODES + 127) / 128, 256, 0, stream>>>(zb, wT1 + 2 * 16384, b1 + 2 * D,
                                                     wT2 + 2 * 16384, b2 + 2 * D,
                                                     xb, hb1, hb2, fwTc, fb, out);
}